// Round 5
// baseline (71.899 us; speedup 1.0000x reference)
//
#include <hip/hip_runtime.h>

// CRPS loss: out = mean(|y_pred - y|) - sum_{i,k,l}|x[i,k]-x[i,l]| / (N*2*M^2)
// N=4096 rows, M=256 ensemble.
//
// R4 post-mortem: O(M^2) pairwise is at its VALU-issue floor (p=2 instr/pair,
// 6.8us). R5 switches algorithm: sorted-rank identity
//   sum_{k,l}|x_k-x_l| = 2 * sum_i (2i+1-M) * x_(i)   (ascending sort)
// via in-register bitonic sort of 256 elems per wave (4 elems/lane,
// element index i = 4*lane + r). 36 substages: j>=4 cross-lane (__shfl_xor,
// 84 shuffles), j=1,2 in-register. ~370 VALU + 84 DS per row vs ~4100 VALU.
// Final reduce merged into kernel1 (1 atomicAdd/block + 4B memset node).

constexpr int N_ROWS = 4096;
constexpr int M_COLS = 256;
constexpr int ROWS_PER_BLOCK = 4;                    // 4 waves x 1 row
constexpr int NUM_BLOCKS = N_ROWS / ROWS_PER_BLOCK;  // 1024

// compare-exchange: up -> (a,b)=(min,max); !up -> (max,min)
__device__ __forceinline__ void ce_dir(float& a, float& b, bool up) {
    const float lo = fminf(a, b);
    const float hi = fmaxf(a, b);
    a = up ? lo : hi;
    b = up ? hi : lo;
}

// cross-lane compare-exchange at element distance 4*xmask
__device__ __forceinline__ void ce_x(float v[4], int xmask, bool keepmin) {
    #pragma unroll
    for (int r = 0; r < 4; ++r) {
        const float w  = __shfl_xor(v[r], xmask, 64);
        const float mn = fminf(v[r], w);
        const float mx = fmaxf(v[r], w);
        v[r] = keepmin ? mn : mx;
    }
}

// merge a K-wide bitonic sequence; `up` = direction of this K-block
template <int K>
__device__ __forceinline__ void bitonic_merge(float v[4], int lane, bool up) {
    #pragma unroll
    for (int j = K / 2; j >= 4; j >>= 1) {
        const bool keepmin = (up == ((lane & (j >> 2)) == 0));
        ce_x(v, j >> 2, keepmin);
    }
    // j = 2, then j = 1 (in-register)
    ce_dir(v[0], v[2], up);
    ce_dir(v[1], v[3], up);
    ce_dir(v[0], v[1], up);
    ce_dir(v[2], v[3], up);
}

__global__ __launch_bounds__(256)
void crps_kernel(const float* __restrict__ y_pred,
                 const float* __restrict__ y,
                 float* __restrict__ out) {
    __shared__ float wsum[ROWS_PER_BLOCK];

    const int wave = threadIdx.x >> 6;               // 0..3 -> row of block
    const int lane = threadIdx.x & 63;
    const int row  = blockIdx.x * ROWS_PER_BLOCK + wave;

    const float4 xk = reinterpret_cast<const float4*>(y_pred + row * M_COLS)[lane];
    const float yi = y[row];                         // wave-uniform

    float v[4] = {xk.x, xk.y, xk.z, xk.w};

    // MAE term (order-independent): compute before the sort permutes values.
    const float mae = fabsf(v[0] - yi) + fabsf(v[1] - yi)
                    + fabsf(v[2] - yi) + fabsf(v[3] - yi);

    // ---- bitonic sort, ascending in element index i = 4*lane + r ----
    // k=2 (j=1): up = ((i&2)==0) -> pair (0,1) asc, (2,3) desc, all lanes.
    ce_dir(v[0], v[1], true);
    ce_dir(v[2], v[3], false);
    bitonic_merge<4>(v, lane, (lane & 1) == 0);      // up = (i&4)==0
    bitonic_merge<8>(v, lane, (lane & 2) == 0);      // up = (i&8)==0
    bitonic_merge<16>(v, lane, (lane & 4) == 0);
    bitonic_merge<32>(v, lane, (lane & 8) == 0);
    bitonic_merge<64>(v, lane, (lane & 16) == 0);
    bitonic_merge<128>(v, lane, (lane & 32) == 0);
    bitonic_merge<256>(v, lane, true);               // final: whole row asc

    // row_mix = sum_p (2p+1-M) * x_(p),  p = 4*lane + r
    const float base = (float)(8 * lane + 1 - M_COLS);
    float rm = 0.0f;
    rm = fmaf(v[0], base + 0.0f, rm);
    rm = fmaf(v[1], base + 2.0f, rm);
    rm = fmaf(v[2], base + 4.0f, rm);
    rm = fmaf(v[3], base + 6.0f, rm);

    // mix_loss = sum_rows 2*row_mix / (N*2*M^2) = sum_rows row_mix / (N*M^2)
    constexpr float mae_scale = 1.0f / ((float)N_ROWS * (float)M_COLS);
    constexpr float mix_scale = 1.0f / ((float)N_ROWS * (float)M_COLS * (float)M_COLS);
    float part = mae * mae_scale - rm * mix_scale;

    // Wave-64 shuffle reduction
    #pragma unroll
    for (int off = 32; off > 0; off >>= 1)
        part += __shfl_down(part, off, 64);

    if (lane == 0) wsum[wave] = part;
    __syncthreads();
    if (threadIdx.x == 0)
        atomicAdd(out, (wsum[0] + wsum[1]) + (wsum[2] + wsum[3]));
}

extern "C" void kernel_launch(void* const* d_in, const int* in_sizes, int n_in,
                              void* d_out, int out_size, void* d_ws, size_t ws_size,
                              hipStream_t stream) {
    const float* y_pred = (const float*)d_in[0];
    const float* y      = (const float*)d_in[1];
    float* out          = (float*)d_out;

    // d_out is poisoned to 0xAA before each timed launch; zero it on-stream.
    hipMemsetAsync(out, 0, sizeof(float), stream);

    crps_kernel<<<NUM_BLOCKS, 256, 0, stream>>>(y_pred, y, out);
}